// Round 7
// baseline (597.405 us; speedup 1.0000x reference)
//
#include <hip/hip_runtime.h>

#define NNODES 25000
#define NEDGES 400000
#define HDIM   32
#define NHEADS 10
#define NCOLS  320          // HEADS*HDIM
#define NEG    0.2f
#define EPSV   1e-5f
#define NQ     40000        // NEDGES/10 edge-groups (16-row tiles, 10 real rows)
#define TPW    10           // tiles per wave
#define GRID_MAIN 1000      // 1000 blocks x 4 waves x 10 tiles = 40000

typedef __bf16 bf16x8 __attribute__((ext_vector_type(8)));
typedef float  f32x4  __attribute__((ext_vector_type(4)));

__device__ __forceinline__ float leaky_f(float v) { return fmaxf(v, NEG * v); }

__device__ __forceinline__ unsigned pk2(float a, float b) {
  unsigned short ua = __builtin_bit_cast(unsigned short, (__bf16)a);
  unsigned short ub = __builtin_bit_cast(unsigned short, (__bf16)b);
  return (unsigned)ua | ((unsigned)ub << 16);
}
__device__ __forceinline__ float bflo(unsigned p) {
  return __builtin_bit_cast(float, p << 16);
}
__device__ __forceinline__ float bfhi(unsigned p) {
  return __builtin_bit_cast(float, p & 0xffff0000u);
}
__device__ __forceinline__ bf16x8 cvt8(float4 a, float4 b) {
  bf16x8 r;
  r[0] = (__bf16)a.x; r[1] = (__bf16)a.y; r[2] = (__bf16)a.z; r[3] = (__bf16)a.w;
  r[4] = (__bf16)b.x; r[5] = (__bf16)b.y; r[6] = (__bf16)b.z; r[7] = (__bf16)b.w;
  return r;
}

__global__ void agat_init_out(float* __restrict__ out, const float* __restrict__ bias) {
  int i = blockIdx.x * 256 + threadIdx.x;
  if (i < NNODES * HDIM) out[i] = bias[i & (HDIM - 1)];
}

// One wave owns one 16-row tile (10 edges + 6 zero pads) completely: all 20
// column slots (10 heads), in-register softmax, zero steady-state barriers.
//   - W^T in LDS (40KB bf16): element (c,k) at byte c*128 + (((k>>3)^(c&7))<<4) + (k&7)*2.
//     Staged with b128 writes (task = (c, k-octet)): 8 lanes sharing c span all 8
//     16B slot-columns -> conflict-free writes; fragment reads are uniform
//     8-lanes-per-slot-column with distinct rows = minimal 8-pass schedule.
//   - A-frags gathered per-lane from global (x/eidx L2-resident, ea streamed).
//   - pass 1: 20 slots x {2 ds_read_b128, 3 MFMA, leaky+att fma} -> logit partials.
//   - 4-step DPP butterfly (16 col-lanes) -> GN affine -> in-register softmax
//     (each lane: 10 heads x its 4 own-quarter rows).
//   - pass 2 recomputes the j-side (2 MFMA/slot; no 40-reg lj array), weights by
//     alpha, 16-row group-sum via shfl16/32, 5 merged 64-lane atomics per tile.
__global__ __launch_bounds__(256, 4) void agat_fused(
    const float* __restrict__ x,
    const int*   __restrict__ eidx,
    const float* __restrict__ ea,
    const float* __restrict__ W,
    const float* __restrict__ att,
    const float* __restrict__ gamma,
    const float* __restrict__ beta,
    const float* __restrict__ rmean,
    const float* __restrict__ rvar,
    float*       __restrict__ out)
{
  const int tid = threadIdx.x;
  const int w  = tid >> 6;   // wave 0..3
  const int l  = tid & 63;
  const int lq = l >> 4;     // quarter: k-slice (A/B), 4-row group (D)
  const int lr = l & 15;     // row (A), col-within-slot (B/D)

  __shared__ __align__(16) __bf16 wt[NCOLS * 64];   // W^T [c][k] bf16, swizzled, 40KB

  // ---- stage W^T once: task = (c 0..319, ko 0..7), one b128 write each ----
  for (int task = tid; task < NCOLS * 8; task += 256) {
    const int c  = task >> 3;
    const int ko = task & 7;
    bf16x8 v;
#pragma unroll
    for (int j = 0; j < 8; ++j) v[j] = (__bf16)W[(8 * ko + j) * NCOLS + c];
    *(bf16x8*)((char*)wt + c * 128 + ((ko ^ (c & 7)) << 4)) = v;
  }

  // ---- per-lane constants: att packed bf16 (20 regs) ----
  unsigned attpk[20];
#pragma unroll
  for (int t = 0; t < 20; ++t) {
    const int h  = t >> 1;
    const int cc = 16 * (t & 1) + lr;
    attpk[t] = pk2(att[h * 64 + cc], att[h * 64 + 32 + cc]);
  }
  // ---- GroupNorm affine -> SGPRs ----
  float gsS[NHEADS], gbS[NHEADS];
#pragma unroll
  for (int h = 0; h < NHEADS; ++h) {
    const float iv = rsqrtf(rvar[h] + EPSV);
    const float a  = iv * gamma[h];
    const float b  = beta[h] - rmean[h] * a;
    gsS[h] = __builtin_bit_cast(float, __builtin_amdgcn_readfirstlane(__builtin_bit_cast(int, a)));
    gbS[h] = __builtin_bit_cast(float, __builtin_amdgcn_readfirstlane(__builtin_bit_cast(int, b)));
  }

  __syncthreads();   // wt visible; the only barrier

  const int wave_id = blockIdx.x * 4 + w;
  const f32x4 zero4 = {0.f, 0.f, 0.f, 0.f};

#pragma unroll 1
  for (int i = 0; i < TPW; ++i) {
    const int q = wave_id * TPW + i;   // tile id < 40000 by construction

    // ---- gather A-fragments (row lr, k-slice lq*8..+7) ----
    bf16x8 xif = (bf16x8)(__bf16)0.0f;
    bf16x8 xjf = (bf16x8)(__bf16)0.0f;
    bf16x8 eaf = (bf16x8)(__bf16)0.0f;
    if (lr < 10) {
      const int e  = q * 10 + lr;
      const int ri = eidx[e];
      const int ci = eidx[NEDGES + e];
      const float* xr = x + ri * HDIM + lq * 8;
      const float* xc = x + ci * HDIM + lq * 8;
      const float* ep = ea + e * HDIM + lq * 8;
      xif = cvt8(*(const float4*)xr, *(const float4*)(xr + 4));
      xjf = cvt8(*(const float4*)xc, *(const float4*)(xc + 4));
      eaf = cvt8(*(const float4*)ep, *(const float4*)(ep + 4));
    }

    // ---- pass 1: 20 slots, logit partials ----
    f32x4 zacc[NHEADS];
#pragma unroll
    for (int h = 0; h < NHEADS; ++h) zacc[h] = zero4;

#pragma unroll
    for (int t = 0; t < 20; ++t) {
      const int c  = 16 * t + lr;      // W^T row (output column)
      const int sw = c & 7;
      const bf16x8 w1 = *(const bf16x8*)((const char*)wt + c * 128 + ((lq ^ sw) << 4));
      const bf16x8 w2 = *(const bf16x8*)((const char*)wt + c * 128 + (((lq + 4) ^ sw) << 4));
      const f32x4 cc_ = __builtin_amdgcn_mfma_f32_16x16x32_bf16(eaf, w2, zero4, 0, 0, 0);
      const f32x4 ai  = __builtin_amdgcn_mfma_f32_16x16x32_bf16(xif, w1, cc_, 0, 0, 0);
      const f32x4 aj  = __builtin_amdgcn_mfma_f32_16x16x32_bf16(xjf, w1, cc_, 0, 0, 0);
      const float ti = bflo(attpk[t]);
      const float tj = bfhi(attpk[t]);
      const int h = t >> 1;
#pragma unroll
      for (int p = 0; p < 4; ++p)
        zacc[h][p] += leaky_f(ai[p]) * ti + leaky_f(aj[p]) * tj;
    }

    // ---- butterfly over the 16 column lanes (stays within quarter) ----
#pragma unroll
    for (int m = 1; m <= 8; m <<= 1)
#pragma unroll
      for (int h = 0; h < NHEADS; ++h)
#pragma unroll
        for (int p = 0; p < 4; ++p)
          zacc[h][p] += __shfl_xor(zacc[h][p], m, 64);

    // ---- GN affine + softmax per row (4 own-quarter rows, in-register) ----
#pragma unroll
    for (int p = 0; p < 4; ++p) {
      float zb[NHEADS];
      float mx = -1e30f;
#pragma unroll
      for (int h = 0; h < NHEADS; ++h) {
        zb[h] = leaky_f(zacc[h][p]) * gsS[h] + gbS[h];
        mx = fmaxf(mx, zb[h]);
      }
      float ssum = 0.f;
#pragma unroll
      for (int h = 0; h < NHEADS; ++h) { zb[h] = __expf(zb[h] - mx); ssum += zb[h]; }
      const float inv = 1.0f / ssum;
#pragma unroll
      for (int h = 0; h < NHEADS; ++h) zacc[h][p] = zb[h] * inv;   // alpha
    }

    // ---- pass 2: recompute j-side, weight, 16-row group-sum, merged scatter ----
    int ng[5];
#pragma unroll
    for (int g = 0; g < 5; ++g)
      ng[g] = eidx[(2 * g + (lq >> 1)) * NQ + q];   // dest node for lane's slot

#pragma unroll
    for (int g = 0; g < 5; ++g) {
      float s4[4];
#pragma unroll
      for (int u = 0; u < 4; ++u) {
        const int t = 4 * g + u, h = t >> 1;
        const int c  = 16 * t + lr;
        const int sw = c & 7;
        const bf16x8 w1 = *(const bf16x8*)((const char*)wt + c * 128 + ((lq ^ sw) << 4));
        const bf16x8 w2 = *(const bf16x8*)((const char*)wt + c * 128 + (((lq + 4) ^ sw) << 4));
        const f32x4 cc_ = __builtin_amdgcn_mfma_f32_16x16x32_bf16(eaf, w2, zero4, 0, 0, 0);
        const f32x4 aj  = __builtin_amdgcn_mfma_f32_16x16x32_bf16(xjf, w1, cc_, 0, 0, 0);
        float s = 0.f;
#pragma unroll
        for (int p = 0; p < 4; ++p)
          s += leaky_f(aj[p]) * zacc[h][p];         // pad rows: aj==0
        s += __shfl_xor(s, 16, 64);
        s += __shfl_xor(s, 32, 64);    // all lanes hold the full 16-row sum
        s4[u] = s;
      }
      const float v01 = (lq & 1) ? s4[1] : s4[0];
      const float v23 = (lq & 1) ? s4[3] : s4[2];
      const float v   = (lq & 2) ? v23 : v01;       // slot t = 4g+lq
      atomicAdd(&out[ng[g] * HDIM + 16 * (lq & 1) + lr], 0.1f * v);
    }
  }
}

extern "C" void kernel_launch(void* const* d_in, const int* in_sizes, int n_in,
                              void* d_out, int out_size, void* d_ws, size_t ws_size,
                              hipStream_t stream) {
  const float* x     = (const float*)d_in[0];
  const int*   eidx  = (const int*)  d_in[1];
  const float* ea    = (const float*)d_in[2];
  const float* W     = (const float*)d_in[3];
  const float* att   = (const float*)d_in[4];
  const float* bias  = (const float*)d_in[5];
  const float* gamma = (const float*)d_in[6];
  const float* beta  = (const float*)d_in[7];
  const float* rmean = (const float*)d_in[8];
  const float* rvar  = (const float*)d_in[9];
  float* out = (float*)d_out;

  agat_init_out<<<(NNODES * HDIM + 255) / 256, 256, 0, stream>>>(out, bias);
  agat_fused<<<GRID_MAIN, 256, 0, stream>>>(x, eidx, ea, W, att, gamma, beta,
                                            rmean, rvar, out);
}

// Round 8
// 396.995 us; speedup vs baseline: 1.5048x; 1.5048x over previous
//
#include <hip/hip_runtime.h>

#define NNODES 25000
#define NEDGES 400000
#define HDIM   32
#define NHEADS 10
#define NCOLS  320          // HEADS*HDIM
#define NEG    0.2f
#define EPSV   1e-5f
#define NQ     40000        // NEDGES/10 edge-groups (16-row tiles, 10 real rows)
#define TPW    5            // tiles per wave
#define GRID_MAIN 2000      // 2000 blocks x 4 waves x 5 tiles = 40000

typedef __bf16 bf16x8 __attribute__((ext_vector_type(8)));
typedef float  f32x4  __attribute__((ext_vector_type(4)));

__device__ __forceinline__ float leaky_f(float v) { return fmaxf(v, NEG * v); }

__device__ __forceinline__ unsigned pk2(float a, float b) {
  unsigned short ua = __builtin_bit_cast(unsigned short, (__bf16)a);
  unsigned short ub = __builtin_bit_cast(unsigned short, (__bf16)b);
  return (unsigned)ua | ((unsigned)ub << 16);
}
__device__ __forceinline__ float bflo(unsigned p) {
  return __builtin_bit_cast(float, p << 16);
}
__device__ __forceinline__ float bfhi(unsigned p) {
  return __builtin_bit_cast(float, p & 0xffff0000u);
}
__device__ __forceinline__ bf16x8 cvt8(float4 a, float4 b) {
  bf16x8 r;
  r[0] = (__bf16)a.x; r[1] = (__bf16)a.y; r[2] = (__bf16)a.z; r[3] = (__bf16)a.w;
  r[4] = (__bf16)b.x; r[5] = (__bf16)b.y; r[6] = (__bf16)b.z; r[7] = (__bf16)b.w;
  return r;
}

__global__ void agat_init_out(float* __restrict__ out, const float* __restrict__ bias) {
  int i = blockIdx.x * 256 + threadIdx.x;
  if (i < NNODES * HDIM) out[i] = bias[i & (HDIM - 1)];
}

// One wave owns one 16-row tile (10 edges + 6 zero pads) completely: all 20
// column slots (10 heads), in-register softmax, zero steady-state barriers.
//   - W^T in LDS (40KB bf16): element (c,k) at byte c*128 + (((k>>3)^(c&7))<<4) + (k&7)*2.
//     b128 staging writes (8 lanes sharing c span all 8 slot-columns) and b128
//     fragment reads (8 lanes/slot-column, distinct rows) are both conflict-free
//     (verified: SQ_LDS_BANK_CONFLICT == 0 in round 7).
//   - NO __launch_bounds__ occupancy cap: round 7's (256,4) forced a 128-VGPR cap
//     -> mass scratch spill (1.2GB FETCH). Natural allocation ~160 VGPR, 3 waves/SIMD.
//   - software pipeline: next tile's eidx loads issue at pass-1 start; next tile's
//     x/ea fragment gathers issue after softmax (covered by pass 2).
//   - pass 1: 20 slots x {2 ds_read_b128, 3 MFMA, leaky+att fma} -> logit partials;
//     4-step shfl butterfly; GN affine + in-register softmax (10 heads x 4 rows).
//   - pass 2: recompute j-side (2 MFMA/slot), weight by alpha, shfl16/32 group-sum,
//     5 merged 64-lane atomics per tile.
__global__ __launch_bounds__(256) void agat_fused(
    const float* __restrict__ x,
    const int*   __restrict__ eidx,
    const float* __restrict__ ea,
    const float* __restrict__ W,
    const float* __restrict__ att,
    const float* __restrict__ gamma,
    const float* __restrict__ beta,
    const float* __restrict__ rmean,
    const float* __restrict__ rvar,
    float*       __restrict__ out)
{
  const int tid = threadIdx.x;
  const int w  = tid >> 6;   // wave 0..3
  const int l  = tid & 63;
  const int lq = l >> 4;     // quarter: k-slice (A/B), 4-row group (D)
  const int lr = l & 15;     // row (A), col-within-slot (B/D)

  __shared__ __align__(16) __bf16 wt[NCOLS * 64];   // W^T [c][k] bf16, swizzled, 40KB

  // ---- stage W^T once: task = (c 0..319, ko 0..7), one b128 write each ----
  for (int task = tid; task < NCOLS * 8; task += 256) {
    const int c  = task >> 3;
    const int ko = task & 7;
    bf16x8 v;
#pragma unroll
    for (int j = 0; j < 8; ++j) v[j] = (__bf16)W[(8 * ko + j) * NCOLS + c];
    *(bf16x8*)((char*)wt + c * 128 + ((ko ^ (c & 7)) << 4)) = v;
  }

  // ---- per-lane constants: att packed bf16 (20 regs) ----
  unsigned attpk[20];
#pragma unroll
  for (int t = 0; t < 20; ++t) {
    const int h  = t >> 1;
    const int cc = 16 * (t & 1) + lr;
    attpk[t] = pk2(att[h * 64 + cc], att[h * 64 + 32 + cc]);
  }
  // ---- GroupNorm affine -> SGPRs ----
  float gsS[NHEADS], gbS[NHEADS];
#pragma unroll
  for (int h = 0; h < NHEADS; ++h) {
    const float iv = rsqrtf(rvar[h] + EPSV);
    const float a  = iv * gamma[h];
    const float b  = beta[h] - rmean[h] * a;
    gsS[h] = __builtin_bit_cast(float, __builtin_amdgcn_readfirstlane(__builtin_bit_cast(int, a)));
    gbS[h] = __builtin_bit_cast(float, __builtin_amdgcn_readfirstlane(__builtin_bit_cast(int, b)));
  }

  __syncthreads();   // wt visible; the only barrier

  const int wave_id = blockIdx.x * 4 + w;
  const f32x4 zero4 = {0.f, 0.f, 0.f, 0.f};
  const int q0 = wave_id * TPW;

  // ---- initial gather for tile 0 ----
  bf16x8 xif = (bf16x8)(__bf16)0.0f;
  bf16x8 xjf = (bf16x8)(__bf16)0.0f;
  bf16x8 eaf = (bf16x8)(__bf16)0.0f;
  if (lr < 10) {
    const int e  = q0 * 10 + lr;
    const int ri = eidx[e];
    const int ci = eidx[NEDGES + e];
    const float* xr = x + ri * HDIM + lq * 8;
    const float* xc = x + ci * HDIM + lq * 8;
    const float* ep = ea + e * HDIM + lq * 8;
    xif = cvt8(*(const float4*)xr, *(const float4*)(xr + 4));
    xjf = cvt8(*(const float4*)xc, *(const float4*)(xc + 4));
    eaf = cvt8(*(const float4*)ep, *(const float4*)(ep + 4));
  }

#pragma unroll 1
  for (int i = 0; i < TPW; ++i) {
    const int q = q0 + i;

    // ---- early: next tile's edge indices + this tile's scatter dests ----
    const int qn = (i + 1 < TPW) ? q + 1 : q;    // guarded (last iter re-gathers)
    int nri = 0, nci = 0;
    if (lr < 10) {
      nri = eidx[qn * 10 + lr];
      nci = eidx[NEDGES + qn * 10 + lr];
    }
    int ng[5];
#pragma unroll
    for (int g = 0; g < 5; ++g)
      ng[g] = eidx[(2 * g + (lq >> 1)) * NQ + q];   // dest node for lane's slot

    // ---- pass 1: 20 slots, logit partials ----
    f32x4 zacc[NHEADS];
#pragma unroll
    for (int h = 0; h < NHEADS; ++h) zacc[h] = zero4;

#pragma unroll
    for (int t = 0; t < 20; ++t) {
      const int c  = 16 * t + lr;      // W^T row (output column)
      const int sw = c & 7;
      const bf16x8 w1 = *(const bf16x8*)((const char*)wt + c * 128 + ((lq ^ sw) << 4));
      const bf16x8 w2 = *(const bf16x8*)((const char*)wt + c * 128 + (((lq + 4) ^ sw) << 4));
      const f32x4 cc_ = __builtin_amdgcn_mfma_f32_16x16x32_bf16(eaf, w2, zero4, 0, 0, 0);
      const f32x4 ai  = __builtin_amdgcn_mfma_f32_16x16x32_bf16(xif, w1, cc_, 0, 0, 0);
      const f32x4 aj  = __builtin_amdgcn_mfma_f32_16x16x32_bf16(xjf, w1, cc_, 0, 0, 0);
      const float ti = bflo(attpk[t]);
      const float tj = bfhi(attpk[t]);
      const int h = t >> 1;
#pragma unroll
      for (int p = 0; p < 4; ++p)
        zacc[h][p] += leaky_f(ai[p]) * ti + leaky_f(aj[p]) * tj;
    }

    // ---- butterfly over the 16 column lanes (stays within quarter) ----
#pragma unroll
    for (int m = 1; m <= 8; m <<= 1)
#pragma unroll
      for (int h = 0; h < NHEADS; ++h)
#pragma unroll
        for (int p = 0; p < 4; ++p)
          zacc[h][p] += __shfl_xor(zacc[h][p], m, 64);

    // ---- GN affine + softmax per row (4 own-quarter rows, in-register) ----
#pragma unroll
    for (int p = 0; p < 4; ++p) {
      float zb[NHEADS];
      float mx = -1e30f;
#pragma unroll
      for (int h = 0; h < NHEADS; ++h) {
        zb[h] = leaky_f(zacc[h][p]) * gsS[h] + gbS[h];
        mx = fmaxf(mx, zb[h]);
      }
      float ssum = 0.f;
#pragma unroll
      for (int h = 0; h < NHEADS; ++h) { zb[h] = __expf(zb[h] - mx); ssum += zb[h]; }
      const float inv = 1.0f / ssum;
#pragma unroll
      for (int h = 0; h < NHEADS; ++h) zacc[h][p] = zb[h] * inv;   // alpha
    }

    // ---- prefetch next tile's fragments (covered by pass 2) ----
    bf16x8 nxif = (bf16x8)(__bf16)0.0f;
    bf16x8 nxjf = (bf16x8)(__bf16)0.0f;
    bf16x8 neaf = (bf16x8)(__bf16)0.0f;
    if (lr < 10) {
      const float* xr = x + nri * HDIM + lq * 8;
      const float* xc = x + nci * HDIM + lq * 8;
      const float* ep = ea + (qn * 10 + lr) * HDIM + lq * 8;
      nxif = cvt8(*(const float4*)xr, *(const float4*)(xr + 4));
      nxjf = cvt8(*(const float4*)xc, *(const float4*)(xc + 4));
      neaf = cvt8(*(const float4*)ep, *(const float4*)(ep + 4));
    }

    // ---- pass 2: recompute j-side, weight, 16-row group-sum, merged scatter ----
#pragma unroll
    for (int g = 0; g < 5; ++g) {
      float s4[4];
#pragma unroll
      for (int u = 0; u < 4; ++u) {
        const int t = 4 * g + u, h = t >> 1;
        const int c  = 16 * t + lr;
        const int sw = c & 7;
        const bf16x8 w1 = *(const bf16x8*)((const char*)wt + c * 128 + ((lq ^ sw) << 4));
        const bf16x8 w2 = *(const bf16x8*)((const char*)wt + c * 128 + (((lq + 4) ^ sw) << 4));
        const f32x4 cc_ = __builtin_amdgcn_mfma_f32_16x16x32_bf16(eaf, w2, zero4, 0, 0, 0);
        const f32x4 aj  = __builtin_amdgcn_mfma_f32_16x16x32_bf16(xjf, w1, cc_, 0, 0, 0);
        float s = 0.f;
#pragma unroll
        for (int p = 0; p < 4; ++p)
          s += leaky_f(aj[p]) * zacc[h][p];         // pad rows: aj==0
        s += __shfl_xor(s, 16, 64);
        s += __shfl_xor(s, 32, 64);    // all lanes hold the full 16-row sum
        s4[u] = s;
      }
      const float v01 = (lq & 1) ? s4[1] : s4[0];
      const float v23 = (lq & 1) ? s4[3] : s4[2];
      const float v   = (lq & 2) ? v23 : v01;       // slot t = 4g+lq
      atomicAdd(&out[ng[g] * HDIM + 16 * (lq & 1) + lr], 0.1f * v);
    }

    // ---- rotate pipeline ----
    xif = nxif; xjf = nxjf; eaf = neaf;
  }
}

extern "C" void kernel_launch(void* const* d_in, const int* in_sizes, int n_in,
                              void* d_out, int out_size, void* d_ws, size_t ws_size,
                              hipStream_t stream) {
  const float* x     = (const float*)d_in[0];
  const int*   eidx  = (const int*)  d_in[1];
  const float* ea    = (const float*)d_in[2];
  const float* W     = (const float*)d_in[3];
  const float* att   = (const float*)d_in[4];
  const float* bias  = (const float*)d_in[5];
  const float* gamma = (const float*)d_in[6];
  const float* beta  = (const float*)d_in[7];
  const float* rmean = (const float*)d_in[8];
  const float* rvar  = (const float*)d_in[9];
  float* out = (float*)d_out;

  agat_init_out<<<(NNODES * HDIM + 255) / 256, 256, 0, stream>>>(out, bias);
  agat_fused<<<GRID_MAIN, 256, 0, stream>>>(x, eidx, ea, W, att, gamma, beta,
                                            rmean, rvar, out);
}

// Round 10
// 353.522 us; speedup vs baseline: 1.6899x; 1.1230x over previous
//
#include <hip/hip_runtime.h>

#define NNODES 25000
#define NEDGES 400000
#define HDIM   32
#define NHEADS 10
#define NCOLS  320          // HEADS*HDIM
#define NEG    0.2f
#define EPSV   1e-5f
#define NQ     40000        // NEDGES/10 edge-groups (16-row tiles, 10 real rows)
#define TPW    4            // tiles per wave
#define GRID_MAIN 1250      // 1250 blocks x 8 waves x 4 tiles = 40000

typedef __bf16 bf16x8 __attribute__((ext_vector_type(8)));
typedef float  f32x4  __attribute__((ext_vector_type(4)));

__device__ __forceinline__ float leaky_f(float v) { return fmaxf(v, NEG * v); }

__device__ __forceinline__ unsigned pk2(float a, float b) {
  unsigned short ua = __builtin_bit_cast(unsigned short, (__bf16)a);
  unsigned short ub = __builtin_bit_cast(unsigned short, (__bf16)b);
  return (unsigned)ua | ((unsigned)ub << 16);
}
__device__ __forceinline__ float bflo(unsigned p) {
  return __builtin_bit_cast(float, p << 16);
}
__device__ __forceinline__ float bfhi(unsigned p) {
  return __builtin_bit_cast(float, p & 0xffff0000u);
}
__device__ __forceinline__ bf16x8 cvt8(float4 a, float4 b) {
  bf16x8 r;
  r[0] = (__bf16)a.x; r[1] = (__bf16)a.y; r[2] = (__bf16)a.z; r[3] = (__bf16)a.w;
  r[4] = (__bf16)b.x; r[5] = (__bf16)b.y; r[6] = (__bf16)b.z; r[7] = (__bf16)b.w;
  return r;
}

// x += neighbor(x) on the VALU pipe via DPP mov. CTRL is a compile-time imm.
template <int CTRL>
__device__ __forceinline__ float dpp_add(float x) {
  const int xi = __builtin_bit_cast(int, x);
  const int y  = __builtin_amdgcn_update_dpp(0, xi, CTRL, 0xf, 0xf, false);
  return x + __builtin_bit_cast(float, y);
}
// All-lanes sum over each 16-lane row (same result on every lane of the row):
// xor1 (quad_perm[1,0,3,2]=0xB1), xor2 (quad_perm[2,3,0,1]=0x4E) make each
// 4-group uniform; then row_ror:4 (0x124) and row_ror:8 (0x128) add the other
// 4-groups (uniformity makes rotation equivalent to xor). Pure VALU, no DS.
__device__ __forceinline__ float bfly16(float x) {
  x = dpp_add<0xB1>(x);
  x = dpp_add<0x4E>(x);
  x = dpp_add<0x124>(x);
  x = dpp_add<0x128>(x);
  return x;
}

__global__ void agat_init_out(float* __restrict__ out, const float* __restrict__ bias) {
  int i = blockIdx.x * 256 + threadIdx.x;
  if (i < NNODES * HDIM) out[i] = bias[i & (HDIM - 1)];
}

// One wave owns one 16-row tile (10 edges + 6 zero pads) completely: all 20
// column slots (10 heads), softmax computed redundantly on ALL lanes (the
// round-8-passing structure), zero steady-state barriers.
// Changes vs the 397us passing version (each independently low-risk):
//   - 16-lane logit reduction on DPP (bfly16, VALU pipe) instead of 4x shfl_xor
//     (DS pipe): value-identical all-lanes butterfly, -160 DS ops/tile.
//   - att table in LDS (packed u32 [20][16]; 16 distinct words/read -> 16 banks,
//     same-address lanes broadcast = conflict-free) instead of 20 VGPRs.
//   - no cross-tile prefetch (rely on TLP), -14 VGPR.
//   - W^T reads from two base pointers + immediate offsets t*2048.
//   - 512-thread blocks: LDS 42KB -> 3 blocks/CU = 24 waves/CU ceiling.
// W^T LDS layout (verified conflict-free in r7: SQ_LDS_BANK_CONFLICT==0):
//   (c,k) at byte c*128 + (((k>>3)^(c&7))<<4) + (k&7)*2, staged b128.
__global__ __launch_bounds__(512) void agat_fused(
    const float* __restrict__ x,
    const int*   __restrict__ eidx,
    const float* __restrict__ ea,
    const float* __restrict__ W,
    const float* __restrict__ att,
    const float* __restrict__ gamma,
    const float* __restrict__ beta,
    const float* __restrict__ rmean,
    const float* __restrict__ rvar,
    float*       __restrict__ out)
{
  const int tid = threadIdx.x;
  const int w  = tid >> 6;   // wave 0..7
  const int l  = tid & 63;
  const int lq = l >> 4;     // quarter: k-slice (A/B), 4-row group (D)
  const int lr = l & 15;     // row (A), col-within-slot (B/D)

  __shared__ __align__(16) __bf16 wt[NCOLS * 64];   // 40960 B
  __shared__ unsigned attp[20 * 16];                // 1280 B

  // ---- stage W^T once: task = (c 0..319, ko 0..7), one b128 write each ----
  for (int task = tid; task < NCOLS * 8; task += 512) {
    const int c  = task >> 3;
    const int ko = task & 7;
    bf16x8 v;
#pragma unroll
    for (int j = 0; j < 8; ++j) v[j] = (__bf16)W[(8 * ko + j) * NCOLS + c];
    *(bf16x8*)((char*)wt + c * 128 + ((ko ^ (c & 7)) << 4)) = v;
  }
  // ---- stage packed att ----
  if (tid < 320) {
    const int t = tid >> 4, rr = tid & 15;
    const int h = t >> 1, cc = 16 * (t & 1) + rr;
    attp[tid] = pk2(att[h * 64 + cc], att[h * 64 + 32 + cc]);
  }

  // ---- GroupNorm affine -> SGPRs ----
  float gsS[NHEADS], gbS[NHEADS];
#pragma unroll
  for (int h = 0; h < NHEADS; ++h) {
    const float iv = rsqrtf(rvar[h] + EPSV);
    const float a  = iv * gamma[h];
    const float b  = beta[h] - rmean[h] * a;
    gsS[h] = __builtin_bit_cast(float, __builtin_amdgcn_readfirstlane(__builtin_bit_cast(int, a)));
    gbS[h] = __builtin_bit_cast(float, __builtin_amdgcn_readfirstlane(__builtin_bit_cast(int, b)));
  }

  __syncthreads();   // wt/attp visible; the only barrier

  const int wave_id = blockIdx.x * 8 + w;
  const f32x4 zero4 = {0.f, 0.f, 0.f, 0.f};
  const int sw = lr & 7;
  const char* base1 = (const char*)wt + lr * 128 + ((lq ^ sw) << 4);
  const char* base2 = (const char*)wt + lr * 128 + (((lq + 4) ^ sw) << 4);
  const unsigned* attb = attp + lr;

#pragma unroll 1
  for (int i = 0; i < TPW; ++i) {
    const int q = wave_id * TPW + i;   // tile id < 40000 by construction

    // ---- gather A-fragments (row lr, k-slice lq*8..+7) ----
    bf16x8 xif = (bf16x8)(__bf16)0.0f;
    bf16x8 xjf = (bf16x8)(__bf16)0.0f;
    bf16x8 eaf = (bf16x8)(__bf16)0.0f;
    if (lr < 10) {
      const int e  = q * 10 + lr;
      const int ri = eidx[e];
      const int ci = eidx[NEDGES + e];
      const float* xr = x + ri * HDIM + lq * 8;
      const float* xc = x + ci * HDIM + lq * 8;
      const float* ep = ea + e * HDIM + lq * 8;
      xif = cvt8(*(const float4*)xr, *(const float4*)(xr + 4));
      xjf = cvt8(*(const float4*)xc, *(const float4*)(xc + 4));
      eaf = cvt8(*(const float4*)ep, *(const float4*)(ep + 4));
    }

    // ---- pass 1: 20 slots, logit partials ----
    f32x4 zacc[NHEADS];
#pragma unroll
    for (int h = 0; h < NHEADS; ++h) zacc[h] = zero4;

#pragma unroll
    for (int t = 0; t < 20; ++t) {
      const bf16x8 w1 = *(const bf16x8*)(base1 + t * 2048);
      const bf16x8 w2 = *(const bf16x8*)(base2 + t * 2048);
      const unsigned ap = attb[t * 16];
      const f32x4 cc_ = __builtin_amdgcn_mfma_f32_16x16x32_bf16(eaf, w2, zero4, 0, 0, 0);
      const f32x4 ai  = __builtin_amdgcn_mfma_f32_16x16x32_bf16(xif, w1, cc_, 0, 0, 0);
      const f32x4 aj  = __builtin_amdgcn_mfma_f32_16x16x32_bf16(xjf, w1, cc_, 0, 0, 0);
      const float ti = bflo(ap);
      const float tj = bfhi(ap);
      const int h = t >> 1;
#pragma unroll
      for (int p = 0; p < 4; ++p)
        zacc[h][p] += leaky_f(ai[p]) * ti + leaky_f(aj[p]) * tj;
    }

    // ---- all-lanes 16-column reduction on the VALU pipe (DPP butterfly) ----
#pragma unroll
    for (int h = 0; h < NHEADS; ++h)
#pragma unroll
      for (int p = 0; p < 4; ++p)
        zacc[h][p] = bfly16(zacc[h][p]);

    // ---- GN affine + softmax per row (all lanes redundantly, as r8-passing) ----
#pragma unroll
    for (int p = 0; p < 4; ++p) {
      float zb[NHEADS];
      float mx = -1e30f;
#pragma unroll
      for (int h = 0; h < NHEADS; ++h) {
        zb[h] = leaky_f(zacc[h][p]) * gsS[h] + gbS[h];
        mx = fmaxf(mx, zb[h]);
      }
      float ssum = 0.f;
#pragma unroll
      for (int h = 0; h < NHEADS; ++h) { zb[h] = __expf(zb[h] - mx); ssum += zb[h]; }
      const float inv = 1.0f / ssum;
#pragma unroll
      for (int h = 0; h < NHEADS; ++h) zacc[h][p] = zb[h] * inv;   // alpha
    }

    // ---- pass 2: recompute j-side, weight, 16-row group-sum, merged scatter ----
    int ng[5];
#pragma unroll
    for (int g = 0; g < 5; ++g)
      ng[g] = eidx[(2 * g + (lq >> 1)) * NQ + q];   // dest node for lane's slot

#pragma unroll
    for (int g = 0; g < 5; ++g) {
      float s4[4];
#pragma unroll
      for (int u = 0; u < 4; ++u) {
        const int t = 4 * g + u, h = t >> 1;
        const bf16x8 w1 = *(const bf16x8*)(base1 + t * 2048);
        const bf16x8 w2 = *(const bf16x8*)(base2 + t * 2048);
        const f32x4 cc_ = __builtin_amdgcn_mfma_f32_16x16x32_bf16(eaf, w2, zero4, 0, 0, 0);
        const f32x4 aj  = __builtin_amdgcn_mfma_f32_16x16x32_bf16(xjf, w1, cc_, 0, 0, 0);
        float s = 0.f;
#pragma unroll
        for (int p = 0; p < 4; ++p)
          s += leaky_f(aj[p]) * zacc[h][p];         // pad rows: aj==0
        s += __shfl_xor(s, 16, 64);
        s += __shfl_xor(s, 32, 64);    // all lanes hold the full 16-row sum
        s4[u] = s;
      }
      const float v01 = (lq & 1) ? s4[1] : s4[0];
      const float v23 = (lq & 1) ? s4[3] : s4[2];
      const float v   = (lq & 2) ? v23 : v01;       // slot t = 4g+lq
      atomicAdd(&out[ng[g] * HDIM + 16 * (lq & 1) + lr], 0.1f * v);
    }
  }
}

extern "C" void kernel_launch(void* const* d_in, const int* in_sizes, int n_in,
                              void* d_out, int out_size, void* d_ws, size_t ws_size,
                              hipStream_t stream) {
  const float* x     = (const float*)d_in[0];
  const int*   eidx  = (const int*)  d_in[1];
  const float* ea    = (const float*)d_in[2];
  const float* W     = (const float*)d_in[3];
  const float* att   = (const float*)d_in[4];
  const float* bias  = (const float*)d_in[5];
  const float* gamma = (const float*)d_in[6];
  const float* beta  = (const float*)d_in[7];
  const float* rmean = (const float*)d_in[8];
  const float* rvar  = (const float*)d_in[9];
  float* out = (float*)d_out;

  agat_init_out<<<(NNODES * HDIM + 255) / 256, 256, 0, stream>>>(out, bias);
  agat_fused<<<GRID_MAIN, 512, 0, stream>>>(x, eidx, ea, W, att, gamma, beta,
                                            rmean, rvar, out);
}